// Round 19
// baseline (66.265 us; speedup 1.0000x reference)
//
#include <hip/hip_runtime.h>
#include <hip/hip_bf16.h>

namespace {

typedef _Float16 v4h __attribute__((ext_vector_type(4)));
typedef __fp16   h2  __attribute__((ext_vector_type(2)));  // cvt_pkrtz return type
typedef float    v4f __attribute__((ext_vector_type(4)));

constexpr int B = 64, G = 512, D = 128, H = 8, KD = 16, NS = 20;
constexpr float NORM = 0.25f;        // 1/sqrt(KD)
constexpr float L2E  = 1.44269504088896f; // folded into Wq with NORM
constexpr float MFIX = 16.0f;        // fixed log2-domain softmax shift (f16-safe)
constexpr int KP = 20;               // Kl row pad (f16)
constexpr int VP = 520;              // Vt row pad (f16)

__device__ __forceinline__ v4f mfma16(v4h a, v4h b, v4f c) {
  // D = A(16xK16)*B(K16x16)+C. A: lane holds A[l&15][4*(l>>4)+i];
  // B: lane holds B[4*(l>>4)+i][l&15]; D: row=4*(l>>4)+i, col=l&15.
  return __builtin_amdgcn_mfma_f32_16x16x16f16(a, b, c, 0, 0, 0);
}
__device__ __forceinline__ v4h cvt4(float4 v) {
  h2 a = __builtin_amdgcn_cvt_pkrtz(v.x, v.y);
  h2 b = __builtin_amdgcn_cvt_pkrtz(v.z, v.w);
  return v4h{(_Float16)a[0], (_Float16)a[1], (_Float16)b[0], (_Float16)b[1]};
}
__device__ __forceinline__ v4h cvtacc(v4f v) {
  h2 a = __builtin_amdgcn_cvt_pkrtz(v[0], v[1]);
  h2 b = __builtin_amdgcn_cvt_pkrtz(v[2], v[3]);
  return v4h{(_Float16)a[0], (_Float16)a[1], (_Float16)b[0], (_Float16)b[1]};
}
// P = exp2(s) packed to f16 (branch-free; s pre-shifted by -MFIX via MFMA C)
__device__ __forceinline__ void pexp(v4f s0, v4f s1, v4h& p0, v4h& p1) {
  h2 e01 = __builtin_amdgcn_cvt_pkrtz(__builtin_amdgcn_exp2f(s0[0]),
                                      __builtin_amdgcn_exp2f(s0[1]));
  h2 e23 = __builtin_amdgcn_cvt_pkrtz(__builtin_amdgcn_exp2f(s0[2]),
                                      __builtin_amdgcn_exp2f(s0[3]));
  h2 e45 = __builtin_amdgcn_cvt_pkrtz(__builtin_amdgcn_exp2f(s1[0]),
                                      __builtin_amdgcn_exp2f(s1[1]));
  h2 e67 = __builtin_amdgcn_cvt_pkrtz(__builtin_amdgcn_exp2f(s1[2]),
                                      __builtin_amdgcn_exp2f(s1[3]));
  p0 = {(_Float16)e01[0], (_Float16)e01[1], (_Float16)e23[0], (_Float16)e23[1]};
  p1 = {(_Float16)e45[0], (_Float16)e45[1], (_Float16)e67[0], (_Float16)e67[1]};
}

// Raw barriers (R18): keep prefetch loads in flight across barriers.
__device__ __forceinline__ void bar_producer() {
  asm volatile("s_waitcnt lgkmcnt(0)" ::: "memory");
  __builtin_amdgcn_s_barrier();
}
__device__ __forceinline__ void bar_raw() {
  asm volatile("" ::: "memory");
  __builtin_amdgcn_s_barrier();
}

struct SM {                          // 53504 B
  char      ht[16384];               // 64x128 f16 staging, XOR-swizzled
  _Float16  Kl[512 * KP];            // K  [n][kd]  20480 B
  _Float16  Vt[16 * VP];             // V^T[kd][n]  16640 B
};

// One block-worth of work for segment SEG at logical block id bid = hh*64+b.
// R18 structure with STRENGTH-REDUCED staging: per-round addressing is pure
// pointer+=stride except the boundary rounds (VALU issue was the measured
// bottleneck: 38% VALUBusy with only ~8us of math -> ~17us of address calc).
template<int SEG>
__device__ __forceinline__ void seg_body(
    int bid, const float* __restrict__ q, const float* __restrict__ hb,
    const float* __restrict__ Wq, const float* __restrict__ Wk,
    const float* __restrict__ Wv, float* __restrict__ heads, SM& sm)
{
  constexpr int Lq   = SEG == 0 ? 1 : SEG == 1 ? NS : G - 1 - NS;  // 1,20,491
  constexpr int QOFF = SEG == 0 ? 0 : SEG == 1 ? 1  : 1 + NS;
  constexpr int Ln   = SEG == 0 ? G - 1 - NS : SEG == 1 ? G - NS : G; // 491,492,512
  constexpr int NCH  = (Ln + 31) / 32;  // key chunks (16)
  constexpr int NQT  = (Lq + 15) / 16;  // query tiles: 31 / 2 / 1
  constexpr int NRI  = (Lq + 63) / 64;  // Q staging rounds (64-row): 8 / 1 / 1
  constexpr int RSTRIDE = 64 * D / 4;   // 64 rows in float4 units

  const int hh   = bid >> 6;
  const int b    = bid & 63;
  const int tid  = threadIdx.x;
  const int w    = tid >> 6;
  const int lane = tid & 63;
  const int g    = lane >> 4, c = lane & 15;

  // ---- hoisted staging constants (loop-invariant) ----
  const int r0  = tid >> 5;          // base row (i adds 16)
  const int jj  = tid & 31;          // float4 column
  char* lwr[4];                      // LDS write addrs (invariant)
  #pragma unroll
  for (int i = 0; i < 4; ++i) {
    const int r = r0 + 16 * i;
    lwr[i] = sm.ht + r * 256 + ((8 * jj) ^ ((r & 7) << 4));
  }
  // segment row mapping for h: careful form (used in boundary rounds only)
  auto hrow = [&](int n) -> int {
    int nn = n < Ln ? n : Ln - 1;
    if (SEG == 0)      return nn + 1 + NS;
    else if (SEG == 1) return (nn == 0) ? 0 : nn + NS;
    else               return nn;
  };

  float4 rg[4];                      // in-flight 64-row staging tile

  // ---- Phase B: K/V projection, strength-reduced staging ----
  {
    v4h wA[8];                       // waves 0-3: Wk, waves 4-7: Wv
    const float* Wt = (w < 4) ? Wk : Wv;
    #pragma unroll
    for (int dc = 0; dc < 8; ++dc)
      #pragma unroll
      for (int bb = 0; bb < 4; ++bb)
        wA[dc][bb] = (_Float16)Wt[((size_t)hh * D + dc * 16 + 4 * g + bb) * KD + c];

    const int sb = w & 3;
    const float4* hbase = (const float4*)(hb + (size_t)b * G * D);
    // prologue: round 0, careful path (handles SEG1 row-0 special)
    #pragma unroll
    for (int i = 0; i < 4; ++i)
      rg[i] = hbase[(size_t)hrow(r0 + 16 * i) * 32 + jj];
    // stride pointers positioned at round 1 (rows 64.. : affine, no clamp,
    // no row-0 special for any segment; SEG0/1 add constant offset)
    const float4* pp[4];
    {
      const int soff = (SEG == 2) ? 0 : (SEG == 0 ? 1 + NS : NS);
      #pragma unroll
      for (int i = 0; i < 4; ++i)
        pp[i] = hbase + (size_t)(64 + r0 + 16 * i + soff) * 32 + jj;
    }
    for (int t = 0; t < 8; ++t) {
      bar_raw();                     // prev compute done reading ht (no drain)
      #pragma unroll
      for (int i = 0; i < 4; ++i)    // write staged tile t
        *(v4h*)(lwr[i]) = cvt4(rg[i]);
      if (t < 7) {                   // prefetch t+1 (in flight across barriers)
        if (SEG == 2 || t + 1 < 7) { // pure stride (rows <= 447 unclamped)
          #pragma unroll
          for (int i = 0; i < 4; ++i) { rg[i] = *pp[i]; pp[i] += RSTRIDE; }
        } else {                     // t+1 == 7, SEG0/1: clamp rows >= Ln
          #pragma unroll
          for (int i = 0; i < 4; ++i)
            rg[i] = hbase[(size_t)hrow(448 + r0 + 16 * i) * 32 + jj];
        }
      }
      bar_producer();                // lgkmcnt(0) only: ht tile t visible
      const int base = t * 64;
      v4f acc = {0.f, 0.f, 0.f, 0.f};
      #pragma unroll
      for (int dc = 0; dc < 8; ++dc) {
        const v4h a = *(const v4h*)(sm.ht + (sb * 16 + c) * 256 +
                                    ((32 * dc + 8 * g) ^ ((c & 7) << 4)));
        acc = mfma16(a, wA[dc], acc);
      }
      if (w < 4) {                   // D: row n = 4g+r (in 16-tile), col kd = c
        #pragma unroll
        for (int r = 0; r < 4; ++r)
          sm.Kl[(base + sb * 16 + 4 * g + r) * KP + c] = (_Float16)acc[r];
      } else {
        v4h vv = {(_Float16)acc[0], (_Float16)acc[1], (_Float16)acc[2], (_Float16)acc[3]};
        *(v4h*)(sm.Vt + c * VP + base + sb * 16 + 4 * g) = vv;
      }
    }
  }

  // ---- Q projection (swapped operands -> in-register qf), single pass ----
  v4h qf[4] = {};
  {
    v4h wQ[8];
    #pragma unroll
    for (int dc = 0; dc < 8; ++dc)
      #pragma unroll
      for (int bb = 0; bb < 4; ++bb)
        wQ[dc][bb] = (_Float16)(Wq[((size_t)hh * D + dc * 16 + 4 * g + bb) * KD + c]
                                * (NORM * L2E));
    const float4* qbase = (const float4*)(q + ((size_t)b * G + QOFF) * D);
    auto qrow = [&](int n) -> int { return n < Lq ? n : Lq - 1; };
    #pragma unroll
    for (int i = 0; i < 4; ++i)      // prologue: round 0, careful
      rg[i] = qbase[(size_t)qrow(r0 + 16 * i) * 32 + jj];
    const float4* qpp[4];
    #pragma unroll
    for (int i = 0; i < 4; ++i)
      qpp[i] = qbase + (size_t)(64 + r0 + 16 * i) * 32 + jj;
    #pragma unroll
    for (int ri = 0; ri < NRI; ++ri) {
      bar_raw();                     // prev readers of ht done
      #pragma unroll
      for (int i = 0; i < 4; ++i)
        *(v4h*)(lwr[i]) = cvt4(rg[i]);
      if (ri + 1 < NRI) {            // prefetch ri+1
        if (ri + 1 < 7) {            // pure stride (rows <= 447 < Lq=491)
          #pragma unroll
          for (int i = 0; i < 4; ++i) { rg[i] = *qpp[i]; qpp[i] += RSTRIDE; }
        } else {                     // last round: clamp rows >= Lq
          #pragma unroll
          for (int i = 0; i < 4; ++i)
            rg[i] = qbase[(size_t)qrow(448 + r0 + 16 * i) * 32 + jj];
        }
      }
      bar_producer();                // ht round ri visible
      if ((w >> 2) == (ri & 1)) {
        const int sl = w & 3;        // tile slot within this round's 64 rows
        const int t  = 4 * ri + sl;  // global tile index = w + 8*(ri>>1)
        if (t < NQT) {
          v4f acc = {0.f, 0.f, 0.f, 0.f};
          #pragma unroll
          for (int dc = 0; dc < 8; ++dc) {
            const v4h a = *(const v4h*)(sm.ht + (sl * 16 + c) * 256 +
                                        ((32 * dc + 8 * g) ^ ((c & 7) << 4)));
            acc = mfma16(wQ[dc], a, acc);   // SWAPPED: D = Qproj^T
          }
          qf[ri >> 1] = cvtacc(acc); // lane (g,c) holds Q[q=c][kd=4g+i]
        }
      }
    }
  }
  // no barrier: attention reads only Kl/Vt; ht is dead until block end.

  // ---- attention: 4 independent chains (tiles w, w+8, w+16, w+24) ----
  {
    const _Float16* Kb = sm.Kl + c * KP + 4 * g;
    const _Float16* Vb = sm.Vt + c * VP + 4 * g;
    const v4f mc = {-MFIX, -MFIX, -MFIX, -MFIX};
    const v4h ones = {(_Float16)1.f, (_Float16)1.f, (_Float16)1.f, (_Float16)1.f};
    v4f o[4]  = {{0.f,0.f,0.f,0.f},{0.f,0.f,0.f,0.f},{0.f,0.f,0.f,0.f},{0.f,0.f,0.f,0.f}};
    v4f la[4] = {{0.f,0.f,0.f,0.f},{0.f,0.f,0.f,0.f},{0.f,0.f,0.f,0.f},{0.f,0.f,0.f,0.f}};
    __builtin_amdgcn_s_setprio(1);   // T5
    #pragma unroll
    for (int ch = 0; ch < NCH; ++ch) {
      const int nb = ch * 32;
      const v4h k0 = *(const v4h*)(Kb + nb * KP);
      const v4h k1 = *(const v4h*)(Kb + (nb + 16) * KP);
      const v4h v0 = *(const v4h*)(Vb + nb);
      const v4h v1 = *(const v4h*)(Vb + nb + 16);
      #pragma unroll
      for (int j = 0; j < 4; ++j) {
        if (w + 8 * j < NQT) {       // wave-uniform guard (j compile-time)
          v4f s0 = mfma16(k0, qf[j], mc);   // (S-m): n=nb+4g+r, q=c
          v4f s1 = mfma16(k1, qf[j], mc);
          if constexpr ((Ln & 31) != 0) {   // tail-key mask (clamped dups)
            if (ch == NCH - 1) {
              #pragma unroll
              for (int r = 0; r < 4; ++r) {
                if (nb + 4 * g + r >= Ln)      s0[r] = -1e30f;
                if (nb + 16 + 4 * g + r >= Ln) s1[r] = -1e30f;
              }
            }
          }
          v4h p0, p1;
          pexp(s0, s1, p0, p1);
          o[j]  = mfma16(v0, p0, o[j]);     // O^T += V^T * P^T
          o[j]  = mfma16(v1, p1, o[j]);
          la[j] = mfma16(ones, p0, la[j]);
          la[j] = mfma16(ones, p1, la[j]);
        }
      }
    }
    __builtin_amdgcn_s_setprio(0);
    // direct store: lane (g,c) holds kd 4g..4g+3 of query c -> one float4
    #pragma unroll
    for (int j = 0; j < 4; ++j) {
      if (w + 8 * j < NQT) {
        const float inv = 1.0f / la[j][0];  // colsum replicated across rows
        const int qloc = (w + 8 * j) * 16 + c;
        if (qloc < Lq) {
          float4 val = {o[j][0]*inv, o[j][1]*inv, o[j][2]*inv, o[j][3]*inv};
          *(float4*)(heads + ((size_t)b * G + QOFF + qloc) * 128 + hh * 16 + 4 * g) = val;
        }
      }
    }
  }
}

// All three segments in one launch, SEG2 first. Within each 512-range
// bid%8 = b%8 -> blocks touching h[b] share an XCD.
__global__ __launch_bounds__(512, 4)
void fused_attn(const float* __restrict__ q, const float* __restrict__ hb,
                const float* __restrict__ Wqd, const float* __restrict__ Wkc,
                const float* __restrict__ Wvc, const float* __restrict__ Wqs,
                const float* __restrict__ Wko, const float* __restrict__ Wvo,
                const float* __restrict__ Wqc, const float* __restrict__ Wka,
                const float* __restrict__ Wva, float* __restrict__ heads)
{
  __shared__ SM sm;
  const int bid = blockIdx.x;
  if (bid < 512)       seg_body<2>(bid,        q, hb, Wqc, Wka, Wva, heads, sm);
  else if (bid < 1024) seg_body<1>(bid - 512,  q, hb, Wqs, Wko, Wvo, heads, sm);
  else                 seg_body<0>(bid - 1024, q, hb, Wqd, Wkc, Wvc, heads, sm);
}

// MFMA output projection, in place: row (b,g) of `data` holds heads[h*16+k]
// (128 values); out[b,g,e] = sum_k heads[k] * Wout[k][e]. 64 rows per block,
// 4 waves; Wout staged transposed [e][k] so B-fragments are v4h reads.
__global__ __launch_bounds__(256)
void out_proj_kernel(float* __restrict__ data, const float* __restrict__ Wout)
{
  __shared__ _Float16 WlT[128 * 132];  // [e][k], 33792 B
  __shared__ _Float16 Ah [64 * 132];   // [row][k], 16896 B
  const int tid  = threadIdx.x;
  const int lane = tid & 63, w = tid >> 6;
  const int g = lane >> 4, c = lane & 15;
  const size_t rowbase = (size_t)blockIdx.x * 64;

  #pragma unroll
  for (int i = 0; i < 16; ++i) {       // stage Wout^T (whole 128x128)
    int idx = tid + i * 256;
    int k = idx >> 5, c4 = (idx & 31) * 4;
    float4 v = ((const float4*)Wout)[idx];
    WlT[(c4 + 0) * 132 + k] = (_Float16)v.x;
    WlT[(c4 + 1) * 132 + k] = (_Float16)v.y;
    WlT[(c4 + 2) * 132 + k] = (_Float16)v.z;
    WlT[(c4 + 3) * 132 + k] = (_Float16)v.w;
  }
  #pragma unroll
  for (int i = 0; i < 8; ++i) {        // stage 64 A rows as f16
    int idx = tid + i * 256;
    int r = idx >> 5, c4 = (idx & 31) * 4;
    float4 v = ((const float4*)(data + rowbase * 128))[idx];
    *(v4h*)(Ah + r * 132 + c4) = cvt4(v);
  }
  __syncthreads();

  v4h af[8];
  #pragma unroll
  for (int dc = 0; dc < 8; ++dc)
    af[dc] = *(const v4h*)(Ah + (w * 16 + c) * 132 + dc * 16 + 4 * g);
  #pragma unroll
  for (int ct = 0; ct < 8; ++ct) {
    v4f acc = {0.f, 0.f, 0.f, 0.f};
    #pragma unroll
    for (int dc = 0; dc < 8; ++dc) {
      const v4h bf = *(const v4h*)(WlT + (ct * 16 + c) * 132 + dc * 16 + 4 * g);
      acc = mfma16(af[dc], bf, acc);
    }
    #pragma unroll
    for (int r = 0; r < 4; ++r)
      data[(rowbase + w * 16 + 4 * g + r) * 128 + ct * 16 + c] = acc[r];
  }
}

} // namespace

extern "C" void kernel_launch(void* const* d_in, const int* in_sizes, int n_in,
                              void* d_out, int out_size, void* d_ws, size_t ws_size,
                              hipStream_t stream) {
  const float* q    = (const float*)d_in[0];
  const float* h    = (const float*)d_in[1];
  const float* Wqd  = (const float*)d_in[2];
  const float* Wkc  = (const float*)d_in[3];
  const float* Wvc  = (const float*)d_in[4];
  const float* Wqs  = (const float*)d_in[5];
  const float* Wko  = (const float*)d_in[6];
  const float* Wvo  = (const float*)d_in[7];
  const float* Wqc  = (const float*)d_in[8];
  const float* Wka  = (const float*)d_in[9];
  const float* Wva  = (const float*)d_in[10];
  const float* Wout = (const float*)d_in[11];
  float* out = (float*)d_out;  // heads buffer, then transformed in place

  fused_attn<<<3 * B * H, 512, 0, stream>>>(q, h, Wqd, Wkc, Wvc,
                                            Wqs, Wko, Wvo, Wqc, Wka, Wva, out);
  out_proj_kernel<<<G * B / 64, 256, 0, stream>>>(out, Wout);
}